// Round 18
// baseline (757.030 us; speedup 1.0000x reference)
//
#include <hip/hip_runtime.h>
#include <hip/hip_bf16.h>
#include <stdint.h>

#define DIM 3072
#define SEQ 4096
#define NH 24
#define HD 128

typedef __hip_bfloat16 bf16;
typedef __bf16 bfv8 __attribute__((ext_vector_type(8)));
typedef float f32x4 __attribute__((ext_vector_type(4)));
typedef float f32x16 __attribute__((ext_vector_type(16)));
typedef unsigned short us4 __attribute__((ext_vector_type(4)));
typedef unsigned short us8 __attribute__((ext_vector_type(8)));

template <int N> struct ic { static constexpr int value = N; };

__device__ __forceinline__ void async16(void* lds, const void* g) {
  __builtin_amdgcn_global_load_lds((const __attribute__((address_space(1))) void*)g,
                                   (__attribute__((address_space(3))) void*)lds, 16, 0, 0);
}

__device__ __forceinline__ unsigned short f2bf(float f) {
  unsigned int u = __builtin_bit_cast(unsigned int, f);
  u += 0x7fffu + ((u >> 16) & 1u);
  return (unsigned short)(u >> 16);
}
__device__ __forceinline__ float bf2f(unsigned short b) {
  return __builtin_bit_cast(float, (unsigned int)b << 16);
}
__device__ __forceinline__ unsigned int cvtpk(float lo, float hi) {
  unsigned int r;
  asm("v_cvt_pk_bf16_f32 %0, %1, %2" : "=v"(r) : "v"(lo), "v"(hi));
  return r;
}
__device__ __forceinline__ void pl32swap(unsigned int& a, unsigned int& b) {
  asm volatile("v_permlane32_swap_b32 %0, %1" : "+v"(a), "+v"(b));
}
#if __has_builtin(__builtin_amdgcn_exp2f)
__device__ __forceinline__ float fexp2(float x) { return __builtin_amdgcn_exp2f(x); }
#else
__device__ __forceinline__ float fexp2(float x) { return exp2f(x); }
#endif

#define MFMA16(a, b, c) __builtin_amdgcn_mfma_f32_16x16x32_bf16((a), (b), (c), 0, 0, 0)
#define MFMA32(a, b, c) __builtin_amdgcn_mfma_f32_32x32x16_bf16((a), (b), (c), 0, 0, 0)

// ------ kernel 1: merged prep. z<3: transpose-cast W -> WT bf16; z==3: cast hs -> bf16 ------
__global__ __launch_bounds__(256) void k_prep(const float* __restrict__ hs,
    us4* __restrict__ hsb, const float* __restrict__ W0, const float* __restrict__ W1,
    const float* __restrict__ W2, unsigned short* __restrict__ T0,
    unsigned short* __restrict__ T1, unsigned short* __restrict__ T2) {
  int z = blockIdx.z;
  int t = threadIdx.x;
  if (z == 3) {
    const int n4 = SEQ * DIM / 4;
    const int stride = 48 * 48 * 256;
    const float4* in = (const float4*)hs;
    for (int i = (blockIdx.y * 48 + blockIdx.x) * 256 + t; i < n4; i += stride) {
      float4 v = in[i];
      us4 r;
      r.x = f2bf(v.x); r.y = f2bf(v.y); r.z = f2bf(v.z); r.w = f2bf(v.w);
      hsb[i] = r;
    }
    return;
  }
  const float* W = (z == 0) ? W0 : (z == 1) ? W1 : W2;
  unsigned short* T = (z == 0) ? T0 : (z == 1) ? T1 : T2;
  int kb = blockIdx.y * 64;
  int nb = blockIdx.x * 64;
  __shared__ float tile[64 * 64];
#pragma unroll
  for (int p = 0; p < 4; ++p) {
    int cid = p * 256 + t;
    int row = cid >> 4, c4 = cid & 15;
    int slot = (c4 + (row >> 3)) & 15;
    float4 v = *(const float4*)&W[(size_t)(kb + row) * DIM + nb + c4 * 4];
    *(float4*)&tile[row * 64 + slot * 4] = v;
  }
  __syncthreads();
#pragma unroll
  for (int p = 0; p < 2; ++p) {
    int cid = p * 256 + t;
    int nl = cid >> 3, c8 = cid & 7;
    us8 o;
#pragma unroll
    for (int j = 0; j < 8; ++j) {
      int k = c8 * 8 + j;
      int slot = ((nl >> 2) + (k >> 3)) & 15;
      o[j] = f2bf(tile[k * 64 + slot * 4 + (nl & 3)]);
    }
    *(us8*)&T[(size_t)(nb + nl) * DIM + kb + c8 * 8] = o;
  }
}

// ------------- kernel 2: GEMM 128x128 + fused RMSNorm/RoPE (q,k) / V^T scatter (v) ----
__global__ __launch_bounds__(256, 3) void k_gemm(const unsigned short* __restrict__ A,
    const unsigned short* __restrict__ B0, const unsigned short* __restrict__ B1,
    const unsigned short* __restrict__ B2, const float* __restrict__ c0,
    const float* __restrict__ c1, const float* __restrict__ c2,
    const float* __restrict__ cosT, const float* __restrict__ sinT,
    const float* __restrict__ gq, const float* __restrict__ gk,
    unsigned short* __restrict__ o0, unsigned short* __restrict__ o1,
    unsigned short* __restrict__ o2) {
  const int b = blockIdx.x;
  const int yb = b % 32;
  const int r2b = b / 32;
  const int xb = r2b % 24;
  const int z = r2b / 24;
  const unsigned short* Bt = (z == 0) ? B0 : (z == 1) ? B1 : B2;
  const float* bias = (z == 0) ? c0 : (z == 1) ? c1 : c2;
  unsigned short* outp = (z == 0) ? o0 : (z == 1) ? o1 : o2;
  const int nb = xb * 128;
  const int mb = yb * 128;
  const int t = threadIdx.x;
  const int w = t >> 6, l = t & 63;
  const int wr = w >> 1, wc = w & 1;
  const int lq = l & 15, lg = l >> 4;
  __shared__ unsigned short lA[128 * 64];
  __shared__ unsigned short lB[128 * 64];
  __shared__ float lds_sq[128 * 2];
  f32x4 acc[4][4];
#pragma unroll
  for (int i = 0; i < 4; ++i)
#pragma unroll
    for (int j = 0; j < 4; ++j) acc[i][j] = (f32x4){0.f, 0.f, 0.f, 0.f};

  for (int kb = 0; kb < DIM; kb += 64) {
    __syncthreads();
#pragma unroll
    for (int r = 0; r < 4; ++r) {
      int row = (w * 4 + r) * 8 + (l >> 3);
      int sl = (l & 7) ^ (row & 7);
      async16(&lA[(w * 4 + r) * 512], A + (size_t)(mb + row) * DIM + kb + sl * 8);
      async16(&lB[(w * 4 + r) * 512], Bt + (size_t)(nb + row) * DIM + kb + sl * 8);
    }
    __syncthreads();
#pragma unroll
    for (int kc = 0; kc < 2; ++kc) {
      bfv8 af[4], bfv[4];
#pragma unroll
      for (int mf = 0; mf < 4; ++mf) {
        int row = wr * 64 + mf * 16 + lq;
        af[mf] = *(const bfv8*)&lA[row * 64 + (((kc * 4 + lg) ^ (row & 7)) * 8)];
      }
#pragma unroll
      for (int nf = 0; nf < 4; ++nf) {
        int row = wc * 64 + nf * 16 + lq;
        bfv[nf] = *(const bfv8*)&lB[row * 64 + (((kc * 4 + lg) ^ (row & 7)) * 8)];
      }
#pragma unroll
      for (int mf = 0; mf < 4; ++mf)
#pragma unroll
        for (int nf = 0; nf < 4; ++nf)
          acc[mf][nf] = MFMA16(af[mf], bfv[nf], acc[mf][nf]);
    }
  }

  float bv4[4];
#pragma unroll
  for (int nf = 0; nf < 4; ++nf) bv4[nf] = bias[nb + wc * 64 + nf * 16 + lq];
#pragma unroll
  for (int mf = 0; mf < 4; ++mf)
#pragma unroll
    for (int nf = 0; nf < 4; ++nf)
#pragma unroll
      for (int r = 0; r < 4; ++r) acc[mf][nf][r] += bv4[nf];

  const int hh = nb >> 7;

  if (z == 2) {  // V: write V^T directly
    unsigned short* vbase = outp + (size_t)hh * HD * SEQ;
#pragma unroll
    for (int nf = 0; nf < 4; ++nf) {
      int dd = wc * 64 + nf * 16 + lq;
#pragma unroll
      for (int mf = 0; mf < 4; ++mf) {
        int s0 = mb + wr * 64 + mf * 16 + lg * 4;
        us4 pk;
#pragma unroll
        for (int r = 0; r < 4; ++r) pk[r] = f2bf(acc[mf][nf][r]);
        *(us4*)&vbase[(size_t)dd * SEQ + s0] = pk;
      }
    }
    return;
  }

  unsigned short* obase0 = outp + (size_t)hh * SEQ * HD;

  float psum[4][4];
#pragma unroll
  for (int mf = 0; mf < 4; ++mf)
#pragma unroll
    for (int r = 0; r < 4; ++r) {
      float p = acc[mf][0][r] * acc[mf][0][r];
      p += acc[mf][1][r] * acc[mf][1][r];
      p += acc[mf][2][r] * acc[mf][2][r];
      p += acc[mf][3][r] * acc[mf][3][r];
      p += __shfl_xor(p, 1);
      p += __shfl_xor(p, 2);
      p += __shfl_xor(p, 4);
      p += __shfl_xor(p, 8);
      psum[mf][r] = p;
    }
  if (lq == 0) {
#pragma unroll
    for (int mf = 0; mf < 4; ++mf)
#pragma unroll
      for (int r = 0; r < 4; ++r)
        lds_sq[(wr * 64 + mf * 16 + lg * 4 + r) * 2 + wc] = psum[mf][r];
  }
  __syncthreads();

  const float* g = (z == 0) ? gq : gk;
  float gvec[4];
#pragma unroll
  for (int nf = 0; nf < 4; ++nf) gvec[nf] = g[wc * 64 + nf * 16 + lq];
  const float qs = (z == 0) ? 0.1275174373f : 1.0f;

#pragma unroll
  for (int mf = 0; mf < 4; ++mf)
#pragma unroll
    for (int r = 0; r < 4; ++r) {
      int row = wr * 64 + mf * 16 + lg * 4 + r;
      float tot = lds_sq[row * 2] + lds_sq[row * 2 + 1];
      float rrv = rsqrtf(tot * (1.0f / 128.0f) + 1e-6f);
      int s = mb + row;
#pragma unroll
      for (int nf = 0; nf < 4; ++nf) {
        int dd = wc * 64 + nf * 16 + lq;
        float y = acc[mf][nf][r] * rrv * gvec[nf];
        float yp = __shfl_xor(y, 1);
        float cc = cosT[s * HD + dd], sn = sinT[s * HD + dd];
        float o = (lq & 1) ? fmaf(yp, sn, y * cc) : fmaf(-yp, sn, y * cc);
        obase0[(size_t)s * HD + dd] = f2bf(o * qs);
      }
    }
}

// ------------- kernel 3: flash attention, R18: single 32KB pair-buffer + reg
// staging (T14) -> 3 blocks/CU, all 768 blocks co-resident (zero quantization).
// Per phase: issue 8 dwordx4 -> regs (pair t+1) | compute pair t from LDS |
// __syncthreads (reads done + vmcnt0) | 8 ds_write_b128 | __syncthreads.
__global__ __launch_bounds__(256, 3) void k_attn(const unsigned short* __restrict__ qg,
    const unsigned short* __restrict__ kg, const unsigned short* __restrict__ vtg,
    float* __restrict__ outp) {
  const int bflat = blockIdx.x;
  const int h = bflat % 24;
  const int qb0 = (bflat / 24) * 128;
  const int t = threadIdx.x;
  const int w = t >> 6, l = t & 63;
  const int l31 = l & 31, hi = l >> 5;

  __shared__ unsigned short lK[8192];  // [64 kv][128 d], swizzled
  __shared__ unsigned short lV[8192];  // [128 d][64 kv], swizzled

  bfv8 qf[8];
  {
    const unsigned short* qrow = qg + ((size_t)h * SEQ + qb0 + w * 32 + l31) * HD + hi * 8;
#pragma unroll
    for (int ks = 0; ks < 8; ++ks) qf[ks] = *(const bfv8*)(qrow + ks * 16);
  }

  int kidx[8], vidx[4][2];
#pragma unroll
  for (int ks = 0; ks < 8; ++ks)
    kidx[ks] = l31 * 128 + (((ks * 2 + hi) ^ (l31 & 7) ^ ((l31 >> 3) & 1)) * 8);
#pragma unroll
  for (int dt = 0; dt < 4; ++dt)
#pragma unroll
    for (int ksub = 0; ksub < 2; ++ksub)
      vidx[dt][ksub] =
          (dt * 32 + l31) * 32 + (((ksub * 2 + hi) ^ (l31 & 3) ^ ((l31 >> 2) & 3)) * 8);

  const unsigned short *kp0, *kp1, *vp0, *vp1;
  {
    int kr0_ = w * 4 + (l >> 4), kr1_ = 16 + kr0_;
    kp0 = kg + ((size_t)h * SEQ + kr0_) * HD + (((l & 15) ^ (kr0_ & 7) ^ ((kr0_ >> 3) & 1)) * 8);
    kp1 = kg + ((size_t)h * SEQ + kr1_) * HD + (((l & 15) ^ (kr1_ & 7) ^ ((kr1_ >> 3) & 1)) * 8);
    int vr0_ = w * 16 + (l >> 2), vr1_ = 64 + vr0_;
    vp0 = vtg + ((size_t)h * HD + vr0_) * SEQ + (((l & 3) ^ (vr0_ & 3) ^ ((vr0_ >> 2) & 3)) * 8);
    vp1 = vtg + ((size_t)h * HD + vr1_) * SEQ + (((l & 3) ^ (vr1_ & 3) ^ ((vr1_ >> 2) & 3)) * 8);
  }

  uint4 krg[4], vrg[4];
#define LOADPAIR()                                                            \
  do {                                                                        \
    krg[0] = *(const uint4*)kp0;                                              \
    krg[1] = *(const uint4*)kp1;                                              \
    krg[2] = *(const uint4*)(kp0 + 32 * HD);                                  \
    krg[3] = *(const uint4*)(kp1 + 32 * HD);                                  \
    vrg[0] = *(const uint4*)vp0;                                              \
    vrg[1] = *(const uint4*)vp1;                                              \
    vrg[2] = *(const uint4*)(vp0 + 32);                                       \
    vrg[3] = *(const uint4*)(vp1 + 32);                                       \
    kp0 += 64 * HD; kp1 += 64 * HD; vp0 += 64; vp1 += 64;                     \
  } while (0)
#define WRITEPAIR()                                                           \
  do {                                                                        \
    *(uint4*)&lK[w * 512 + l * 8] = krg[0];                                   \
    *(uint4*)&lK[2048 + w * 512 + l * 8] = krg[1];                            \
    *(uint4*)&lK[4096 + w * 512 + l * 8] = krg[2];                            \
    *(uint4*)&lK[6144 + w * 512 + l * 8] = krg[3];                            \
    *(uint4*)&lV[w * 512 + l * 8] = vrg[0];                                   \
    *(uint4*)&lV[2048 + w * 512 + l * 8] = vrg[1];                            \
    *(uint4*)&lV[4096 + w * 512 + l * 8] = vrg[2];                            \
    *(uint4*)&lV[6144 + w * 512 + l * 8] = vrg[3];                            \
  } while (0)

  f32x16 oacc[4];
#pragma unroll
  for (int dt = 0; dt < 4; ++dt)
#pragma unroll
    for (int r = 0; r < 16; ++r) oacc[dt][r] = 0.f;
  float l_run = 0.f;

  // prologue: pair 0 -> regs -> LDS
  LOADPAIR();
  __syncthreads();  // vmcnt(0): regs landed
  WRITEPAIR();
  __syncthreads();  // writes visible

  for (int tt = 0; tt < 64; ++tt) {
    if (tt < 63) LOADPAIR();  // pair tt+1 in flight under compute

    // ---- two independent QK chains over the pair in LDS ----
    f32x16 sa, sb;
#pragma unroll
    for (int r = 0; r < 16; ++r) { sa[r] = 0.f; sb[r] = 0.f; }
    __builtin_amdgcn_s_setprio(1);
#pragma unroll
    for (int ks = 0; ks < 8; ++ks) {
      bfv8 kfa = *(const bfv8*)&lK[kidx[ks]];
      bfv8 kfb = *(const bfv8*)&lK[4096 + kidx[ks]];
      sa = MFMA32(kfa, qf[ks], sa);
      sb = MFMA32(kfb, qf[ks], sb);
    }
    __builtin_amdgcn_s_setprio(0);

#pragma unroll
    for (int r = 0; r < 16; ++r) { sa[r] = fexp2(sa[r]); sb[r] = fexp2(sb[r]); }
    {
      float a0 = (sa[0] + sa[1]) + (sa[2] + sa[3]);
      float a1 = (sa[4] + sa[5]) + (sa[6] + sa[7]);
      float a2 = (sa[8] + sa[9]) + (sa[10] + sa[11]);
      float a3 = (sa[12] + sa[13]) + (sa[14] + sa[15]);
      float b0 = (sb[0] + sb[1]) + (sb[2] + sb[3]);
      float b1 = (sb[4] + sb[5]) + (sb[6] + sb[7]);
      float b2 = (sb[8] + sb[9]) + (sb[10] + sb[11]);
      float b3 = (sb[12] + sb[13]) + (sb[14] + sb[15]);
      l_run += ((a0 + a1) + (a2 + a3)) + ((b0 + b1) + (b2 + b3));
    }

    bfv8 paA[2], paB[2];
    {
      unsigned int a0 = cvtpk(sa[0], sa[1]), a1 = cvtpk(sa[2], sa[3]);
      unsigned int b0 = cvtpk(sa[4], sa[5]), b1 = cvtpk(sa[6], sa[7]);
      unsigned int c0 = cvtpk(sa[8], sa[9]), c1 = cvtpk(sa[10], sa[11]);
      unsigned int d0 = cvtpk(sa[12], sa[13]), d1 = cvtpk(sa[14], sa[15]);
      pl32swap(a0, b0); pl32swap(a1, b1); pl32swap(c0, d0); pl32swap(c1, d1);
      paA[0] = __builtin_bit_cast(bfv8, make_uint4(a0, a1, b0, b1));
      paA[1] = __builtin_bit_cast(bfv8, make_uint4(c0, c1, d0, d1));
      a0 = cvtpk(sb[0], sb[1]); a1 = cvtpk(sb[2], sb[3]);
      b0 = cvtpk(sb[4], sb[5]); b1 = cvtpk(sb[6], sb[7]);
      c0 = cvtpk(sb[8], sb[9]); c1 = cvtpk(sb[10], sb[11]);
      d0 = cvtpk(sb[12], sb[13]); d1 = cvtpk(sb[14], sb[15]);
      pl32swap(a0, b0); pl32swap(a1, b1); pl32swap(c0, d0); pl32swap(c1, d1);
      paB[0] = __builtin_bit_cast(bfv8, make_uint4(a0, a1, b0, b1));
      paB[1] = __builtin_bit_cast(bfv8, make_uint4(c0, c1, d0, d1));
    }

    __builtin_amdgcn_s_setprio(1);
#pragma unroll
    for (int dt = 0; dt < 4; ++dt) {
#pragma unroll
      for (int ksub = 0; ksub < 2; ++ksub) {
        bfv8 vfa = *(const bfv8*)&lV[vidx[dt][ksub]];
        oacc[dt] = MFMA32(paA[ksub], vfa, oacc[dt]);
      }
#pragma unroll
      for (int ksub = 0; ksub < 2; ++ksub) {
        bfv8 vfb = *(const bfv8*)&lV[4096 + vidx[dt][ksub]];
        oacc[dt] = MFMA32(paB[ksub], vfb, oacc[dt]);
      }
    }
    __builtin_amdgcn_s_setprio(0);

    if (tt < 63) {
      __syncthreads();  // all reads of pair tt done + vmcnt(0): pair tt+1 landed
      WRITEPAIR();
      __syncthreads();  // pair tt+1 visible
    }
  }

  l_run += __shfl_xor(l_run, 32);
  float linv = 1.0f / l_run;
#pragma unroll
  for (int r = 0; r < 16; ++r) {
    int qr = (r & 3) + 8 * (r >> 2) + 4 * hi;
    float lr = __shfl(linv, qr);
    float* orow = outp + (size_t)(qb0 + w * 32 + qr) * DIM + h * HD;
#pragma unroll
    for (int dt = 0; dt < 4; ++dt) orow[dt * 32 + l31] = oacc[dt][r] * lr;
  }
#undef LOADPAIR
#undef WRITEPAIR
}

extern "C" void kernel_launch(void* const* d_in, const int* in_sizes, int n_in,
                              void* d_out, int out_size, void* d_ws, size_t ws_size,
                              hipStream_t stream) {
  const float* hs = (const float*)d_in[0];
  const float* cosT = (const float*)d_in[1];
  const float* sinT = (const float*)d_in[2];
  const float* Wq = (const float*)d_in[3];
  const float* bq = (const float*)d_in[4];
  const float* Wk = (const float*)d_in[5];
  const float* bk = (const float*)d_in[6];
  const float* Wv = (const float*)d_in[7];
  const float* bv = (const float*)d_in[8];
  const float* gq = (const float*)d_in[9];
  const float* gk = (const float*)d_in[10];
  float* out = (float*)d_out;

  char* ws = (char*)d_ws;
  const size_t SZ_HS = (size_t)SEQ * DIM * 2;
  const size_t SZ_W = (size_t)DIM * DIM * 2;
  const size_t SZ_HEAD = (size_t)NH * SEQ * HD * 2;
  unsigned short* hsb = (unsigned short*)ws;               ws += SZ_HS;
  unsigned short* WqT = (unsigned short*)ws;               ws += SZ_W;
  unsigned short* WkT = (unsigned short*)ws;               ws += SZ_W;
  unsigned short* WvT = (unsigned short*)ws;               ws += SZ_W;
  unsigned short* q_b = (unsigned short*)ws;               ws += SZ_HEAD;
  unsigned short* k_b = (unsigned short*)ws;               ws += SZ_HEAD;
  unsigned short* vtr = (unsigned short*)ws;               ws += SZ_HEAD;

  k_prep<<<dim3(48, 48, 4), dim3(256), 0, stream>>>(hs, (us4*)hsb, Wq, Wk, Wv,
                                                    WqT, WkT, WvT);
  k_gemm<<<dim3(2304), dim3(256), 0, stream>>>(hsb, WqT, WkT, WvT, bq, bk, bv,
                                               cosT, sinT, gq, gk, q_b, k_b, vtr);
  k_attn<<<dim3(768), dim3(256), 0, stream>>>(q_b, k_b, vtr, out);
}

// Round 19
// 506.769 us; speedup vs baseline: 1.4938x; 1.4938x over previous
//
#include <hip/hip_runtime.h>
#include <hip/hip_bf16.h>
#include <stdint.h>

#define DIM 3072
#define SEQ 4096
#define NH 24
#define HD 128

typedef __hip_bfloat16 bf16;
typedef __bf16 bfv8 __attribute__((ext_vector_type(8)));
typedef float f32x4 __attribute__((ext_vector_type(4)));
typedef float f32x16 __attribute__((ext_vector_type(16)));
typedef unsigned short us4 __attribute__((ext_vector_type(4)));
typedef unsigned short us8 __attribute__((ext_vector_type(8)));

template <int N> struct ic { static constexpr int value = N; };

__device__ __forceinline__ void async16(void* lds, const void* g) {
  __builtin_amdgcn_global_load_lds((const __attribute__((address_space(1))) void*)g,
                                   (__attribute__((address_space(3))) void*)lds, 16, 0, 0);
}

__device__ __forceinline__ unsigned short f2bf(float f) {
  unsigned int u = __builtin_bit_cast(unsigned int, f);
  u += 0x7fffu + ((u >> 16) & 1u);
  return (unsigned short)(u >> 16);
}
__device__ __forceinline__ float bf2f(unsigned short b) {
  return __builtin_bit_cast(float, (unsigned int)b << 16);
}
__device__ __forceinline__ unsigned int cvtpk(float lo, float hi) {
  unsigned int r;
  asm("v_cvt_pk_bf16_f32 %0, %1, %2" : "=v"(r) : "v"(lo), "v"(hi));
  return r;
}
__device__ __forceinline__ void pl32swap(unsigned int& a, unsigned int& b) {
  asm volatile("v_permlane32_swap_b32 %0, %1" : "+v"(a), "+v"(b));
}
#if __has_builtin(__builtin_amdgcn_exp2f)
__device__ __forceinline__ float fexp2(float x) { return __builtin_amdgcn_exp2f(x); }
#else
__device__ __forceinline__ float fexp2(float x) { return exp2f(x); }
#endif

#define MFMA16(a, b, c) __builtin_amdgcn_mfma_f32_16x16x32_bf16((a), (b), (c), 0, 0, 0)
#define MFMA32(a, b, c) __builtin_amdgcn_mfma_f32_32x32x16_bf16((a), (b), (c), 0, 0, 0)

// ------ kernel 1: merged prep. z<3: transpose-cast W -> WT bf16; z==3: cast hs -> bf16 ------
__global__ __launch_bounds__(256) void k_prep(const float* __restrict__ hs,
    us4* __restrict__ hsb, const float* __restrict__ W0, const float* __restrict__ W1,
    const float* __restrict__ W2, unsigned short* __restrict__ T0,
    unsigned short* __restrict__ T1, unsigned short* __restrict__ T2) {
  int z = blockIdx.z;
  int t = threadIdx.x;
  if (z == 3) {
    const int n4 = SEQ * DIM / 4;
    const int stride = 48 * 48 * 256;
    const float4* in = (const float4*)hs;
    for (int i = (blockIdx.y * 48 + blockIdx.x) * 256 + t; i < n4; i += stride) {
      float4 v = in[i];
      us4 r;
      r.x = f2bf(v.x); r.y = f2bf(v.y); r.z = f2bf(v.z); r.w = f2bf(v.w);
      hsb[i] = r;
    }
    return;
  }
  const float* W = (z == 0) ? W0 : (z == 1) ? W1 : W2;
  unsigned short* T = (z == 0) ? T0 : (z == 1) ? T1 : T2;
  int kb = blockIdx.y * 64;
  int nb = blockIdx.x * 64;
  __shared__ float tile[64 * 64];
#pragma unroll
  for (int p = 0; p < 4; ++p) {
    int cid = p * 256 + t;
    int row = cid >> 4, c4 = cid & 15;
    int slot = (c4 + (row >> 3)) & 15;
    float4 v = *(const float4*)&W[(size_t)(kb + row) * DIM + nb + c4 * 4];
    *(float4*)&tile[row * 64 + slot * 4] = v;
  }
  __syncthreads();
#pragma unroll
  for (int p = 0; p < 2; ++p) {
    int cid = p * 256 + t;
    int nl = cid >> 3, c8 = cid & 7;
    us8 o;
#pragma unroll
    for (int j = 0; j < 8; ++j) {
      int k = c8 * 8 + j;
      int slot = ((nl >> 2) + (k >> 3)) & 15;
      o[j] = f2bf(tile[k * 64 + slot * 4 + (nl & 3)]);
    }
    *(us8*)&T[(size_t)(nb + nl) * DIM + kb + c8 * 8] = o;
  }
}

// ------------- kernel 2: GEMM 128x128 + fused RMSNorm/RoPE (q,k) / V^T scatter (v) ----
__global__ __launch_bounds__(256, 3) void k_gemm(const unsigned short* __restrict__ A,
    const unsigned short* __restrict__ B0, const unsigned short* __restrict__ B1,
    const unsigned short* __restrict__ B2, const float* __restrict__ c0,
    const float* __restrict__ c1, const float* __restrict__ c2,
    const float* __restrict__ cosT, const float* __restrict__ sinT,
    const float* __restrict__ gq, const float* __restrict__ gk,
    unsigned short* __restrict__ o0, unsigned short* __restrict__ o1,
    unsigned short* __restrict__ o2) {
  const int b = blockIdx.x;
  const int yb = b % 32;
  const int r2b = b / 32;
  const int xb = r2b % 24;
  const int z = r2b / 24;
  const unsigned short* Bt = (z == 0) ? B0 : (z == 1) ? B1 : B2;
  const float* bias = (z == 0) ? c0 : (z == 1) ? c1 : c2;
  unsigned short* outp = (z == 0) ? o0 : (z == 1) ? o1 : o2;
  const int nb = xb * 128;
  const int mb = yb * 128;
  const int t = threadIdx.x;
  const int w = t >> 6, l = t & 63;
  const int wr = w >> 1, wc = w & 1;
  const int lq = l & 15, lg = l >> 4;
  __shared__ unsigned short lA[128 * 64];
  __shared__ unsigned short lB[128 * 64];
  __shared__ float lds_sq[128 * 2];
  f32x4 acc[4][4];
#pragma unroll
  for (int i = 0; i < 4; ++i)
#pragma unroll
    for (int j = 0; j < 4; ++j) acc[i][j] = (f32x4){0.f, 0.f, 0.f, 0.f};

  for (int kb = 0; kb < DIM; kb += 64) {
    __syncthreads();
#pragma unroll
    for (int r = 0; r < 4; ++r) {
      int row = (w * 4 + r) * 8 + (l >> 3);
      int sl = (l & 7) ^ (row & 7);
      async16(&lA[(w * 4 + r) * 512], A + (size_t)(mb + row) * DIM + kb + sl * 8);
      async16(&lB[(w * 4 + r) * 512], Bt + (size_t)(nb + row) * DIM + kb + sl * 8);
    }
    __syncthreads();
#pragma unroll
    for (int kc = 0; kc < 2; ++kc) {
      bfv8 af[4], bfv[4];
#pragma unroll
      for (int mf = 0; mf < 4; ++mf) {
        int row = wr * 64 + mf * 16 + lq;
        af[mf] = *(const bfv8*)&lA[row * 64 + (((kc * 4 + lg) ^ (row & 7)) * 8)];
      }
#pragma unroll
      for (int nf = 0; nf < 4; ++nf) {
        int row = wc * 64 + nf * 16 + lq;
        bfv[nf] = *(const bfv8*)&lB[row * 64 + (((kc * 4 + lg) ^ (row & 7)) * 8)];
      }
#pragma unroll
      for (int mf = 0; mf < 4; ++mf)
#pragma unroll
        for (int nf = 0; nf < 4; ++nf)
          acc[mf][nf] = MFMA16(af[mf], bfv[nf], acc[mf][nf]);
    }
  }

  float bv4[4];
#pragma unroll
  for (int nf = 0; nf < 4; ++nf) bv4[nf] = bias[nb + wc * 64 + nf * 16 + lq];
#pragma unroll
  for (int mf = 0; mf < 4; ++mf)
#pragma unroll
    for (int nf = 0; nf < 4; ++nf)
#pragma unroll
      for (int r = 0; r < 4; ++r) acc[mf][nf][r] += bv4[nf];

  const int hh = nb >> 7;

  if (z == 2) {  // V: write V^T directly (vt[h][d][s])
    unsigned short* vbase = outp + (size_t)hh * HD * SEQ;
#pragma unroll
    for (int nf = 0; nf < 4; ++nf) {
      int dd = wc * 64 + nf * 16 + lq;
#pragma unroll
      for (int mf = 0; mf < 4; ++mf) {
        int s0 = mb + wr * 64 + mf * 16 + lg * 4;
        us4 pk;
#pragma unroll
        for (int r = 0; r < 4; ++r) pk[r] = f2bf(acc[mf][nf][r]);
        *(us4*)&vbase[(size_t)dd * SEQ + s0] = pk;
      }
    }
    return;
  }

  unsigned short* obase0 = outp + (size_t)hh * SEQ * HD;

  float psum[4][4];
#pragma unroll
  for (int mf = 0; mf < 4; ++mf)
#pragma unroll
    for (int r = 0; r < 4; ++r) {
      float p = acc[mf][0][r] * acc[mf][0][r];
      p += acc[mf][1][r] * acc[mf][1][r];
      p += acc[mf][2][r] * acc[mf][2][r];
      p += acc[mf][3][r] * acc[mf][3][r];
      p += __shfl_xor(p, 1);
      p += __shfl_xor(p, 2);
      p += __shfl_xor(p, 4);
      p += __shfl_xor(p, 8);
      psum[mf][r] = p;
    }
  if (lq == 0) {
#pragma unroll
    for (int mf = 0; mf < 4; ++mf)
#pragma unroll
      for (int r = 0; r < 4; ++r)
        lds_sq[(wr * 64 + mf * 16 + lg * 4 + r) * 2 + wc] = psum[mf][r];
  }
  __syncthreads();

  const float* g = (z == 0) ? gq : gk;
  float gvec[4];
#pragma unroll
  for (int nf = 0; nf < 4; ++nf) gvec[nf] = g[wc * 64 + nf * 16 + lq];
  const float qs = (z == 0) ? 0.1275174373f : 1.0f;  // log2(e)/sqrt(128) for q

#pragma unroll
  for (int mf = 0; mf < 4; ++mf)
#pragma unroll
    for (int r = 0; r < 4; ++r) {
      int row = wr * 64 + mf * 16 + lg * 4 + r;
      float tot = lds_sq[row * 2] + lds_sq[row * 2 + 1];
      float rrv = rsqrtf(tot * (1.0f / 128.0f) + 1e-6f);
      int s = mb + row;
#pragma unroll
      for (int nf = 0; nf < 4; ++nf) {
        int dd = wc * 64 + nf * 16 + lq;
        float y = acc[mf][nf][r] * rrv * gvec[nf];
        float yp = __shfl_xor(y, 1);
        float cc = cosT[s * HD + dd], sn = sinT[s * HD + dd];
        float o = (lq & 1) ? fmaf(yp, sn, y * cc) : fmaf(-yp, sn, y * cc);
        obase0[(size_t)s * HD + dd] = f2bf(o * qs);
      }
    }
}

// ------------- kernel 3: flash attention (R13 proven form: 2 pair-buffers,
// gload_lds staging, head-congruent XCD clustering; best measured 237 us) -------------
__global__ __launch_bounds__(256, 2) void k_attn(const unsigned short* __restrict__ qg,
    const unsigned short* __restrict__ kg, const unsigned short* __restrict__ vtg,
    float* __restrict__ outp) {
  const int bflat = blockIdx.x;
  const int h = bflat % 24;
  const int qb0 = (bflat / 24) * 128;
  const int t = threadIdx.x;
  const int w = t >> 6, l = t & 63;
  const int l31 = l & 31, hi = l >> 5;

  __shared__ unsigned short lKf[2 * 8192];
  __shared__ unsigned short lVf[2 * 8192];

  bfv8 qf[8];
  {
    const unsigned short* qrow = qg + ((size_t)h * SEQ + qb0 + w * 32 + l31) * HD + hi * 8;
#pragma unroll
    for (int ks = 0; ks < 8; ++ks) qf[ks] = *(const bfv8*)(qrow + ks * 16);
  }

  int kidx[8], vidx[4][2];
#pragma unroll
  for (int ks = 0; ks < 8; ++ks)
    kidx[ks] = l31 * 128 + (((ks * 2 + hi) ^ (l31 & 7) ^ ((l31 >> 3) & 1)) * 8);
#pragma unroll
  for (int dt = 0; dt < 4; ++dt)
#pragma unroll
    for (int ksub = 0; ksub < 2; ++ksub)
      vidx[dt][ksub] =
          (dt * 32 + l31) * 32 + (((ksub * 2 + hi) ^ (l31 & 3) ^ ((l31 >> 2) & 3)) * 8);

  const unsigned short *kp0, *kp1, *vp0, *vp1;
  {
    int kr0 = w * 4 + (l >> 4), kr1 = 16 + kr0;
    kp0 = kg + ((size_t)h * SEQ + kr0) * HD + (((l & 15) ^ (kr0 & 7) ^ ((kr0 >> 3) & 1)) * 8);
    kp1 = kg + ((size_t)h * SEQ + kr1) * HD + (((l & 15) ^ (kr1 & 7) ^ ((kr1 >> 3) & 1)) * 8);
    int vr0 = w * 16 + (l >> 2), vr1 = 64 + vr0;
    vp0 = vtg + ((size_t)h * HD + vr0) * SEQ + (((l & 3) ^ (vr0 & 3) ^ ((vr0 >> 2) & 3)) * 8);
    vp1 = vtg + ((size_t)h * HD + vr1) * SEQ + (((l & 3) ^ (vr1 & 3) ^ ((vr1 >> 2) & 3)) * 8);
  }

#define STAGE(B)                                                              \
  do {                                                                        \
    async16(&lKf[(B) * 8192 + w * 512], kp0);                                 \
    async16(&lKf[(B) * 8192 + 2048 + w * 512], kp1);                          \
    async16(&lKf[(B) * 8192 + 4096 + w * 512], kp0 + 32 * HD);                \
    async16(&lKf[(B) * 8192 + 6144 + w * 512], kp1 + 32 * HD);                \
    async16(&lVf[(B) * 8192 + w * 512], vp0);                                 \
    async16(&lVf[(B) * 8192 + 2048 + w * 512], vp1);                          \
    async16(&lVf[(B) * 8192 + 4096 + w * 512], vp0 + 32);                     \
    async16(&lVf[(B) * 8192 + 6144 + w * 512], vp1 + 32);                     \
    kp0 += 64 * HD; kp1 += 64 * HD; vp0 += 64; vp1 += 64;                     \
  } while (0)

  f32x16 oacc[4];
#pragma unroll
  for (int dt = 0; dt < 4; ++dt)
#pragma unroll
    for (int r = 0; r < 16; ++r) oacc[dt][r] = 0.f;
  float l_run = 0.f;

  STAGE(0);

  auto phase = [&](auto bufc, auto stagec) {
    constexpr int CUR = decltype(bufc)::value;
    constexpr int DOSTAGE = decltype(stagec)::value;
    asm volatile("s_waitcnt vmcnt(0)" ::: "memory");
    __builtin_amdgcn_s_barrier();
    __builtin_amdgcn_sched_barrier(0);
    if constexpr (DOSTAGE) STAGE(CUR ^ 1);
    __builtin_amdgcn_sched_barrier(0);

    f32x16 sa, sb;
#pragma unroll
    for (int r = 0; r < 16; ++r) { sa[r] = 0.f; sb[r] = 0.f; }
    __builtin_amdgcn_s_setprio(1);
#pragma unroll
    for (int ks = 0; ks < 8; ++ks) {
      bfv8 kfa = *(const bfv8*)&lKf[CUR * 8192 + kidx[ks]];
      bfv8 kfb = *(const bfv8*)&lKf[CUR * 8192 + 4096 + kidx[ks]];
      sa = MFMA32(kfa, qf[ks], sa);
      sb = MFMA32(kfb, qf[ks], sb);
    }
    __builtin_amdgcn_s_setprio(0);

#pragma unroll
    for (int r = 0; r < 16; ++r) { sa[r] = fexp2(sa[r]); sb[r] = fexp2(sb[r]); }
    {
      float a0 = (sa[0] + sa[1]) + (sa[2] + sa[3]);
      float a1 = (sa[4] + sa[5]) + (sa[6] + sa[7]);
      float a2 = (sa[8] + sa[9]) + (sa[10] + sa[11]);
      float a3 = (sa[12] + sa[13]) + (sa[14] + sa[15]);
      float b0 = (sb[0] + sb[1]) + (sb[2] + sb[3]);
      float b1 = (sb[4] + sb[5]) + (sb[6] + sb[7]);
      float b2 = (sb[8] + sb[9]) + (sb[10] + sb[11]);
      float b3 = (sb[12] + sb[13]) + (sb[14] + sb[15]);
      l_run += ((a0 + a1) + (a2 + a3)) + ((b0 + b1) + (b2 + b3));
    }

    bfv8 paA[2], paB[2];
    {
      unsigned int a0 = cvtpk(sa[0], sa[1]), a1 = cvtpk(sa[2], sa[3]);
      unsigned int b0 = cvtpk(sa[4], sa[5]), b1 = cvtpk(sa[6], sa[7]);
      unsigned int c0 = cvtpk(sa[8], sa[9]), c1 = cvtpk(sa[10], sa[11]);
      unsigned int d0 = cvtpk(sa[12], sa[13]), d1 = cvtpk(sa[14], sa[15]);
      pl32swap(a0, b0); pl32swap(a1, b1); pl32swap(c0, d0); pl32swap(c1, d1);
      paA[0] = __builtin_bit_cast(bfv8, make_uint4(a0, a1, b0, b1));
      paA[1] = __builtin_bit_cast(bfv8, make_uint4(c0, c1, d0, d1));
      a0 = cvtpk(sb[0], sb[1]); a1 = cvtpk(sb[2], sb[3]);
      b0 = cvtpk(sb[4], sb[5]); b1 = cvtpk(sb[6], sb[7]);
      c0 = cvtpk(sb[8], sb[9]); c1 = cvtpk(sb[10], sb[11]);
      d0 = cvtpk(sb[12], sb[13]); d1 = cvtpk(sb[14], sb[15]);
      pl32swap(a0, b0); pl32swap(a1, b1); pl32swap(c0, d0); pl32swap(c1, d1);
      paB[0] = __builtin_bit_cast(bfv8, make_uint4(a0, a1, b0, b1));
      paB[1] = __builtin_bit_cast(bfv8, make_uint4(c0, c1, d0, d1));
    }

    __builtin_amdgcn_s_setprio(1);
#pragma unroll
    for (int dt = 0; dt < 4; ++dt) {
#pragma unroll
      for (int ksub = 0; ksub < 2; ++ksub) {
        bfv8 vfa = *(const bfv8*)&lVf[CUR * 8192 + vidx[dt][ksub]];
        oacc[dt] = MFMA32(paA[ksub], vfa, oacc[dt]);
      }
#pragma unroll
      for (int ksub = 0; ksub < 2; ++ksub) {
        bfv8 vfb = *(const bfv8*)&lVf[CUR * 8192 + 4096 + vidx[dt][ksub]];
        oacc[dt] = MFMA32(paB[ksub], vfb, oacc[dt]);
      }
    }
    __builtin_amdgcn_s_setprio(0);
  };

  for (int it = 0; it < 31; ++it) {
    phase(ic<0>{}, ic<1>{});
    phase(ic<1>{}, ic<1>{});
  }
  phase(ic<0>{}, ic<1>{});
  phase(ic<1>{}, ic<0>{});

  l_run += __shfl_xor(l_run, 32);
  float linv = 1.0f / l_run;
#pragma unroll
  for (int r = 0; r < 16; ++r) {
    int qr = (r & 3) + 8 * (r >> 2) + 4 * hi;
    float lr = __shfl(linv, qr);
    float* orow = outp + (size_t)(qb0 + w * 32 + qr) * DIM + h * HD;
#pragma unroll
    for (int dt = 0; dt < 4; ++dt) orow[dt * 32 + l31] = oacc[dt][r] * lr;
  }
#undef STAGE
}

extern "C" void kernel_launch(void* const* d_in, const int* in_sizes, int n_in,
                              void* d_out, int out_size, void* d_ws, size_t ws_size,
                              hipStream_t stream) {
  const float* hs = (const float*)d_in[0];
  const float* cosT = (const float*)d_in[1];
  const float* sinT = (const float*)d_in[2];
  const float* Wq = (const float*)d_in[3];
  const float* bq = (const float*)d_in[4];
  const float* Wk = (const float*)d_in[5];
  const float* bk = (const float*)d_in[6];
  const float* Wv = (const float*)d_in[7];
  const float* bv = (const float*)d_in[8];
  const float* gq = (const float*)d_in[9];
  const float* gk = (const float*)d_in[10];
  float* out = (float*)d_out;

  char* ws = (char*)d_ws;
  const size_t SZ_HS = (size_t)SEQ * DIM * 2;
  const size_t SZ_W = (size_t)DIM * DIM * 2;
  const size_t SZ_HEAD = (size_t)NH * SEQ * HD * 2;
  unsigned short* hsb = (unsigned short*)ws;               ws += SZ_HS;
  unsigned short* WqT = (unsigned short*)ws;               ws += SZ_W;
  unsigned short* WkT = (unsigned short*)ws;               ws += SZ_W;
  unsigned short* WvT = (unsigned short*)ws;               ws += SZ_W;
  unsigned short* q_b = (unsigned short*)ws;               ws += SZ_HEAD;
  unsigned short* k_b = (unsigned short*)ws;               ws += SZ_HEAD;
  unsigned short* vtr = (unsigned short*)ws;               ws += SZ_HEAD;

  k_prep<<<dim3(48, 48, 4), dim3(256), 0, stream>>>(hs, (us4*)hsb, Wq, Wk, Wv,
                                                    WqT, WkT, WvT);
  k_gemm<<<dim3(2304), dim3(256), 0, stream>>>(hsb, WqT, WkT, WvT, bq, bk, bv,
                                               cosT, sinT, gq, gk, q_b, k_b, vtr);
  k_attn<<<dim3(768), dim3(256), 0, stream>>>(q_b, k_b, vtr, out);
}